// Round 12
// baseline (3954.100 us; speedup 1.0000x reference)
//
#include <hip/hip_runtime.h>

#define N_NODES 100000
#define N_EDGES 1600000
#define HD 128
#define NH (N_NODES * HD)

typedef __attribute__((ext_vector_type(8))) short bf16x8;
typedef __attribute__((ext_vector_type(4))) float f32x4;

__device__ inline unsigned short f2bf(float f) {
  unsigned u = __float_as_uint(f);
  unsigned r = (u + 0x7FFFu + ((u >> 16) & 1u)) >> 16;
  return (unsigned short)r;
}
__device__ inline float bf2f(unsigned short b) {
  return __uint_as_float(((unsigned)b) << 16);
}
__device__ inline float sigm_f(float x) {
  return __builtin_amdgcn_rcpf(1.f + __expf(-x));
}
__device__ inline float tanh_f(float x) {
  return 1.f - 2.f * __builtin_amdgcn_rcpf(__expf(2.f * x) + 1.f);
}

// ---------------------------------------------------------------------------
// h0 GEMM: h0b = bf16(node_embed @ node_w^T + node_b)
// ---------------------------------------------------------------------------
__global__ __launch_bounds__(256) void gemm_h0_k(
    const float* __restrict__ A, const float* __restrict__ B,
    const float* __restrict__ bias, unsigned short* __restrict__ Cb, int M) {
  __shared__ float As[16][132];
  __shared__ float Bs[16][68];
  const int tid = threadIdx.x;
  const int row0 = blockIdx.x * 128;
  const int col0 = blockIdx.y * 64;
  const int tx = tid & 15, ty = tid >> 4;

  float acc[8][4];
#pragma unroll
  for (int i = 0; i < 8; i++)
#pragma unroll
    for (int j = 0; j < 4; j++) acc[i][j] = 0.f;

  const int lr = tid >> 2;
  const int kg = (tid & 3) * 4;

  for (int k0 = 0; k0 < 128; k0 += 16) {
#pragma unroll
    for (int h = 0; h < 2; ++h) {
      int r = lr + h * 64;
      float4 v = make_float4(0.f, 0.f, 0.f, 0.f);
      if (row0 + r < M)
        v = *reinterpret_cast<const float4*>(A + (size_t)(row0 + r) * 128 + k0 + kg);
      As[kg + 0][r] = v.x;
      As[kg + 1][r] = v.y;
      As[kg + 2][r] = v.z;
      As[kg + 3][r] = v.w;
    }
    {
      int c = lr;
      float4 v = *reinterpret_cast<const float4*>(B + (size_t)(col0 + c) * 128 + k0 + kg);
      Bs[kg + 0][c] = v.x;
      Bs[kg + 1][c] = v.y;
      Bs[kg + 2][c] = v.z;
      Bs[kg + 3][c] = v.w;
    }
    __syncthreads();
#pragma unroll
    for (int kk = 0; kk < 16; ++kk) {
      float a[8], b[4];
#pragma unroll
      for (int i = 0; i < 8; i++) a[i] = As[kk][ty * 8 + i];
#pragma unroll
      for (int j = 0; j < 4; j++) b[j] = Bs[kk][tx * 4 + j];
#pragma unroll
      for (int i = 0; i < 8; i++)
#pragma unroll
        for (int j = 0; j < 4; j++) acc[i][j] += a[i] * b[j];
    }
    __syncthreads();
  }

#pragma unroll
  for (int i = 0; i < 8; i++) {
    int r = row0 + ty * 8 + i;
    if (r < M) {
#pragma unroll
      for (int j = 0; j < 4; j++) {
        int c = col0 + tx * 4 + j;
        Cb[(size_t)r * 128 + c] = f2bf(acc[i][j] + bias[c]);
      }
    }
  }
}

// ---------------------------------------------------------------------------
// Batched WcT fold: C[z] = w_ih[z>>2] @ ggc_w[z]^T   ([384,128] each, z=0..15)
// ---------------------------------------------------------------------------
__global__ __launch_bounds__(256) void gemm_wct_k(
    const float* __restrict__ w_ih, const float* __restrict__ ggc_w,
    float* __restrict__ Cout) {
  const int z = blockIdx.z;
  const float* A = w_ih + (size_t)(z >> 2) * 384 * 128;
  const float* B = ggc_w + (size_t)z * 128 * 128;
  float* C = Cout + (size_t)z * 384 * 128;
  __shared__ float As[16][132];
  __shared__ float Bs[16][68];
  const int tid = threadIdx.x;
  const int row0 = blockIdx.x * 128;
  const int col0 = blockIdx.y * 64;
  const int tx = tid & 15, ty = tid >> 4;

  float acc[8][4];
#pragma unroll
  for (int i = 0; i < 8; i++)
#pragma unroll
    for (int j = 0; j < 4; j++) acc[i][j] = 0.f;

  const int lr = tid >> 2;
  const int kg = (tid & 3) * 4;

  for (int k0 = 0; k0 < 128; k0 += 16) {
#pragma unroll
    for (int h = 0; h < 2; ++h) {
      int r = lr + h * 64;
      float4 v = *reinterpret_cast<const float4*>(A + (size_t)(row0 + r) * 128 + k0 + kg);
      As[kg + 0][r] = v.x;
      As[kg + 1][r] = v.y;
      As[kg + 2][r] = v.z;
      As[kg + 3][r] = v.w;
    }
    {
      int c = lr;
      float4 v = *reinterpret_cast<const float4*>(B + (size_t)(col0 + c) * 128 + k0 + kg);
      Bs[kg + 0][c] = v.x;
      Bs[kg + 1][c] = v.y;
      Bs[kg + 2][c] = v.z;
      Bs[kg + 3][c] = v.w;
    }
    __syncthreads();
#pragma unroll
    for (int kk = 0; kk < 16; ++kk) {
      float a[8], b[4];
#pragma unroll
      for (int i = 0; i < 8; i++) a[i] = As[kk][ty * 8 + i];
#pragma unroll
      for (int j = 0; j < 4; j++) b[j] = Bs[kk][tx * 4 + j];
#pragma unroll
      for (int i = 0; i < 8; i++)
#pragma unroll
        for (int j = 0; j < 4; j++) acc[i][j] += a[i] * b[j];
    }
    __syncthreads();
  }

#pragma unroll
  for (int i = 0; i < 8; i++) {
    int r = row0 + ty * 8 + i;
#pragma unroll
    for (int j = 0; j < 4; j++) {
      int c = col0 + tx * 4 + j;
      C[(size_t)r * 128 + c] = acc[i][j];
    }
  }
}

// ---------------------------------------------------------------------------
// float -> bf16, 4 elems/thread
// ---------------------------------------------------------------------------
__global__ __launch_bounds__(256) void f2b_k(const float* __restrict__ a,
                                             unsigned short* __restrict__ b, int n) {
  int i = blockIdx.x * 256 + threadIdx.x;
  if (i * 4 >= n) return;
  float4 v = reinterpret_cast<const float4*>(a)[i];
  ushort4 o;
  o.x = f2bf(v.x);
  o.y = f2bf(v.y);
  o.z = f2bf(v.z);
  o.w = f2bf(v.w);
  reinterpret_cast<ushort4*>(b)[i] = o;
}

// ---------------------------------------------------------------------------
// GRU v8: gather FUSED into the GRU. Block = 512 thr (8 waves) per 16-row
// tile (grid-stride), blockIdx.y = chain.
//  Phase A (!GAGG): wave w gathers rows 2w,2w+1 of agg into LDS (XOR-swizzled,
//    double-buffered; lane covers a 2-col pair, 4 edges in flight).
//  Phase B: a_ag fragments from LDS (swizzled), a_x from global Xin; 24 MFMA;
//    GRU epilogue -> Xout (ping-pong buffer, no in-place hazard).
//  GAGG=1 (step 0): agg read from a global buffer (shared by all chains),
//    no LDS, no barrier.
// ---------------------------------------------------------------------------
template <bool GAGG, bool LAST>
__global__ __launch_bounds__(512) void gru_fused8_k(
    const unsigned short* __restrict__ agg_g, size_t agg_zs,
    const unsigned short* __restrict__ Xin_base, size_t xin_zs,
    const unsigned short* __restrict__ h0b,
    const int* __restrict__ offsets, const int* __restrict__ srcs,
    const unsigned short* __restrict__ wct_base, size_t wct_zs,
    const unsigned short* __restrict__ whh_base, size_t whh_zs,
    const float* __restrict__ bih_base, const float* __restrict__ bhh_base,
    unsigned short* __restrict__ Xout, int nRowTiles) {
  __shared__ unsigned short aggs[2][16 * 128];
  const int z = blockIdx.y;
  const unsigned short* agg = agg_g + (size_t)z * agg_zs;
  const unsigned short* xin = Xin_base + (size_t)z * xin_zs;
  unsigned short* xout = Xout + (size_t)z * NH;
  const unsigned short* wctb = wct_base + (size_t)z * wct_zs;
  const unsigned short* whhb = whh_base + (size_t)z * whh_zs;
  const float* b_ih = bih_base + z * 384;
  const float* b_hh = bhh_base + z * 384;

  const int lane = threadIdx.x & 63;
  const int wave = threadIdx.x >> 6;  // 0..7
  const int lrow = lane & 15;
  const int kblk = lane >> 4;  // 0..3
  const int c = wave * 16 + lrow;

  bf16x8 wf[6][4];
#pragma unroll
  for (int s = 0; s < 3; s++)
#pragma unroll
    for (int kk = 0; kk < 4; kk++) {
      size_t off = (size_t)(s * 128 + c) * 128 + kk * 32 + kblk * 8;
      wf[s][kk] = *reinterpret_cast<const bf16x8*>(wctb + off);
      wf[s + 3][kk] = *reinterpret_cast<const bf16x8*>(whhb + off);
    }
  const float bi0 = b_ih[c], bi1 = b_ih[128 + c], bi2 = b_ih[256 + c];
  const float bh0 = b_hh[c], bh1 = b_hh[128 + c], bh2 = b_hh[256 + c];

  int buf = 0;
  for (int rt = blockIdx.x; rt < nRowTiles; rt += gridDim.x, buf ^= 1) {
    const int row0 = rt * 16;  // N_NODES % 16 == 0 -> rows in-bounds

    if (!GAGG) {
      // ---- Phase A: gather 2 rows per wave into swizzled LDS ----
#pragma unroll
      for (int h = 0; h < 2; h++) {
        const int lr = 2 * wave + h;
        const int row = row0 + lr;
        const int beg = offsets[row], end = offsets[row + 1];
        float ax = 0.f, ay = 0.f;
        int e = beg;
        for (; e + 3 < end; e += 4) {
          int s0 = srcs[e], s1 = srcs[e + 1], s2 = srcs[e + 2], s3 = srcs[e + 3];
          unsigned v0 = *reinterpret_cast<const unsigned*>(xin + (size_t)s0 * 128 + lane * 2);
          unsigned v1 = *reinterpret_cast<const unsigned*>(xin + (size_t)s1 * 128 + lane * 2);
          unsigned v2 = *reinterpret_cast<const unsigned*>(xin + (size_t)s2 * 128 + lane * 2);
          unsigned v3 = *reinterpret_cast<const unsigned*>(xin + (size_t)s3 * 128 + lane * 2);
          ax += bf2f((unsigned short)(v0 & 0xFFFFu)) + bf2f((unsigned short)(v1 & 0xFFFFu)) +
                bf2f((unsigned short)(v2 & 0xFFFFu)) + bf2f((unsigned short)(v3 & 0xFFFFu));
          ay += bf2f((unsigned short)(v0 >> 16)) + bf2f((unsigned short)(v1 >> 16)) +
                bf2f((unsigned short)(v2 >> 16)) + bf2f((unsigned short)(v3 >> 16));
        }
        for (; e < end; e++) {
          int s0 = srcs[e];
          unsigned v0 = *reinterpret_cast<const unsigned*>(xin + (size_t)s0 * 128 + lane * 2);
          ax += bf2f((unsigned short)(v0 & 0xFFFFu));
          ay += bf2f((unsigned short)(v0 >> 16));
        }
        unsigned o = (unsigned)f2bf(ax) | ((unsigned)f2bf(ay) << 16);
        unsigned off = (unsigned)(lr * 256 + lane * 4) ^ (unsigned)((lr & 7) << 4);
        *reinterpret_cast<unsigned*>(reinterpret_cast<char*>(aggs[buf]) + off) = o;
      }
      __syncthreads();  // single barrier per tile (LDS double-buffered)
    }

    // ---- Phase B: fragments + MFMA + epilogue ----
    const size_t abase = (size_t)(row0 + lrow) * 128 + kblk * 8;
    bf16x8 a_ag[4], a_x[4];
#pragma unroll
    for (int kk = 0; kk < 4; kk++) {
      if (GAGG) {
        a_ag[kk] = *reinterpret_cast<const bf16x8*>(agg + abase + kk * 32);
      } else {
        unsigned off = (unsigned)(lrow * 256 + kk * 64 + kblk * 16) ^ (unsigned)((lrow & 7) << 4);
        a_ag[kk] = *reinterpret_cast<const bf16x8*>(reinterpret_cast<char*>(aggs[buf]) + off);
      }
      a_x[kk] = *reinterpret_cast<const bf16x8*>(xin + abase + kk * 32);
    }

    f32x4 acc[6];
#pragma unroll
    for (int s = 0; s < 6; s++) acc[s] = (f32x4)(0.f);
#pragma unroll
    for (int kk = 0; kk < 4; kk++) {
      acc[0] = __builtin_amdgcn_mfma_f32_16x16x32_bf16(a_ag[kk], wf[0][kk], acc[0], 0, 0, 0);
      acc[1] = __builtin_amdgcn_mfma_f32_16x16x32_bf16(a_ag[kk], wf[1][kk], acc[1], 0, 0, 0);
      acc[2] = __builtin_amdgcn_mfma_f32_16x16x32_bf16(a_ag[kk], wf[2][kk], acc[2], 0, 0, 0);
      acc[3] = __builtin_amdgcn_mfma_f32_16x16x32_bf16(a_x[kk], wf[3][kk], acc[3], 0, 0, 0);
      acc[4] = __builtin_amdgcn_mfma_f32_16x16x32_bf16(a_x[kk], wf[4][kk], acc[4], 0, 0, 0);
      acc[5] = __builtin_amdgcn_mfma_f32_16x16x32_bf16(a_x[kk], wf[5][kk], acc[5], 0, 0, 0);
    }
    // C/D: col = lane&15 (= lrow -> c), row = kblk*4 + r
#pragma unroll
    for (int r = 0; r < 4; r++) {
      int orow = row0 + kblk * 4 + r;
      size_t idx = (size_t)orow * 128 + c;
      float ir = acc[0][r] + bi0;
      float iz = acc[1][r] + bi1;
      float in_ = acc[2][r] + bi2;
      float hr = acc[3][r] + bh0;
      float hz = acc[4][r] + bh1;
      float hn = acc[5][r] + bh2;
      float rg = sigm_f(ir + hr);
      float zg = sigm_f(iz + hz);
      float ng = tanh_f(in_ + rg * hn);
      float h = bf2f(xin[idx]);
      float nv = (1.f - zg) * ng + zg * h;
      if (LAST) nv += bf2f(h0b[idx]);
      xout[idx] = f2bf(nv);
    }
  }
}

// ---------------------------------------------------------------------------
// cat full: hidden = concat(X[0..3]) @ cat_w^T + cat_b  (K=512, one pass)
// ---------------------------------------------------------------------------
__global__ __launch_bounds__(256) void cat_full_k(
    const unsigned short* __restrict__ X, const unsigned short* __restrict__ wcatb,
    const float* __restrict__ cat_b, float* __restrict__ hidden, int M) {
  const int lane = threadIdx.x & 63;
  const int wave = threadIdx.x >> 6;
  const int row0 = blockIdx.x * 64 + wave * 16;
  const int c0 = blockIdx.y * 32;
  const int lrow = lane & 15;
  const int kb = lane >> 4;
  int arow = row0 + lrow;
  if (arow >= M) arow = M - 1;

  f32x4 acc[2];
  acc[0] = (f32x4)(0.f);
  acc[1] = (f32x4)(0.f);
#pragma unroll
  for (int kk = 0; kk < 16; kk++) {
    const unsigned short* ob = X + (size_t)(kk >> 2) * NH;
    bf16x8 a = *reinterpret_cast<const bf16x8*>(
        ob + (size_t)arow * 128 + (kk & 3) * 32 + kb * 8);
#pragma unroll
    for (int t = 0; t < 2; t++) {
      bf16x8 b = *reinterpret_cast<const bf16x8*>(
          wcatb + (size_t)(c0 + t * 16 + lrow) * 512 + (kk >> 2) * 128 +
          (kk & 3) * 32 + kb * 8);
      acc[t] = __builtin_amdgcn_mfma_f32_16x16x32_bf16(a, b, acc[t], 0, 0, 0);
    }
  }
#pragma unroll
  for (int r = 0; r < 4; r++) {
    int orow = row0 + kb * 4 + r;
    if (orow >= M) continue;
#pragma unroll
    for (int t = 0; t < 2; t++) {
      int c = c0 + t * 16 + lrow;
      hidden[(size_t)orow * 128 + c] = acc[t][r] + cat_b[c];
    }
  }
}

// ---------------------------------------------------------------------------
// CSR build
// ---------------------------------------------------------------------------
__global__ __launch_bounds__(256) void deg_hist_k(const int* __restrict__ dst,
                                                  int* __restrict__ deg) {
  int e = blockIdx.x * 256 + threadIdx.x;
  if (e >= N_EDGES) return;
  atomicAdd(&deg[dst[e]], 1);
}

__global__ __launch_bounds__(256) void scan1_k(const int* __restrict__ deg,
                                               int* __restrict__ offsets,
                                               int* __restrict__ bsum) {
  __shared__ int buf[256];
  int tid = threadIdx.x;
  int idx = blockIdx.x * 256 + tid;
  int v = (idx < N_NODES) ? deg[idx] : 0;
  buf[tid] = v;
  __syncthreads();
  for (int off = 1; off < 256; off <<= 1) {
    int t = (tid >= off) ? buf[tid - off] : 0;
    __syncthreads();
    buf[tid] += t;
    __syncthreads();
  }
  if (idx < N_NODES) offsets[idx] = buf[tid] - v;
  if (tid == 255) bsum[blockIdx.x] = buf[255];
}

__global__ __launch_bounds__(512) void scan2_k(int* __restrict__ bsum, int nb) {
  __shared__ int buf[512];
  int tid = threadIdx.x;
  int v = (tid < nb) ? bsum[tid] : 0;
  buf[tid] = v;
  __syncthreads();
  for (int off = 1; off < 512; off <<= 1) {
    int t = (tid >= off) ? buf[tid - off] : 0;
    __syncthreads();
    buf[tid] += t;
    __syncthreads();
  }
  if (tid < nb) bsum[tid] = buf[tid] - v;
}

__global__ __launch_bounds__(256) void scan3_k(int* __restrict__ offsets,
                                               const int* __restrict__ bsum) {
  int idx = blockIdx.x * 256 + threadIdx.x;
  if (idx < N_NODES) offsets[idx] += bsum[idx >> 8];
  if (idx == 0) offsets[N_NODES] = N_EDGES;
}

__global__ __launch_bounds__(256) void copy_int_k(const int* __restrict__ a,
                                                  int* __restrict__ b, int n) {
  int i = blockIdx.x * 256 + threadIdx.x;
  if (i < n) b[i] = a[i];
}

__global__ __launch_bounds__(256) void fill_k(const int* __restrict__ src,
                                              const int* __restrict__ dst,
                                              int* __restrict__ cursor,
                                              int* __restrict__ srcs_sorted) {
  int e = blockIdx.x * 256 + threadIdx.x;
  if (e >= N_EDGES) return;
  int pos = atomicAdd(&cursor[dst[e]], 1);
  srcs_sorted[pos] = src[e];
}

// ---------------------------------------------------------------------------
// gather (step 0 only, 1 chain): wave per node; 32/32 half-split, 4-deep
// ---------------------------------------------------------------------------
__global__ __launch_bounds__(256) void gather5_k(
    const unsigned short* __restrict__ xb, const int* __restrict__ offsets,
    const int* __restrict__ srcs, unsigned short* __restrict__ aggb) {
  int node = (blockIdx.x * 256 + threadIdx.x) >> 6;
  int lane = threadIdx.x & 63;
  if (node >= N_NODES) return;
  int beg = offsets[node], end = offsets[node + 1];
  int half = lane >> 5;
  int cg = (lane & 31) * 4;
  float a0 = 0.f, a1 = 0.f, a2 = 0.f, a3 = 0.f;
  int e = beg + half;
  for (; e + 6 < end; e += 8) {
    int s0 = srcs[e], s1 = srcs[e + 2], s2 = srcs[e + 4], s3 = srcs[e + 6];
    uint2 v0 = *reinterpret_cast<const uint2*>(xb + (size_t)s0 * 128 + cg);
    uint2 v1 = *reinterpret_cast<const uint2*>(xb + (size_t)s1 * 128 + cg);
    uint2 v2 = *reinterpret_cast<const uint2*>(xb + (size_t)s2 * 128 + cg);
    uint2 v3 = *reinterpret_cast<const uint2*>(xb + (size_t)s3 * 128 + cg);
    a0 += bf2f((unsigned short)(v0.x & 0xFFFFu)) + bf2f((unsigned short)(v1.x & 0xFFFFu)) +
          bf2f((unsigned short)(v2.x & 0xFFFFu)) + bf2f((unsigned short)(v3.x & 0xFFFFu));
    a1 += bf2f((unsigned short)(v0.x >> 16)) + bf2f((unsigned short)(v1.x >> 16)) +
          bf2f((unsigned short)(v2.x >> 16)) + bf2f((unsigned short)(v3.x >> 16));
    a2 += bf2f((unsigned short)(v0.y & 0xFFFFu)) + bf2f((unsigned short)(v1.y & 0xFFFFu)) +
          bf2f((unsigned short)(v2.y & 0xFFFFu)) + bf2f((unsigned short)(v3.y & 0xFFFFu));
    a3 += bf2f((unsigned short)(v0.y >> 16)) + bf2f((unsigned short)(v1.y >> 16)) +
          bf2f((unsigned short)(v2.y >> 16)) + bf2f((unsigned short)(v3.y >> 16));
  }
  for (; e < end; e += 2) {
    int s0 = srcs[e];
    uint2 v0 = *reinterpret_cast<const uint2*>(xb + (size_t)s0 * 128 + cg);
    a0 += bf2f((unsigned short)(v0.x & 0xFFFFu));
    a1 += bf2f((unsigned short)(v0.x >> 16));
    a2 += bf2f((unsigned short)(v0.y & 0xFFFFu));
    a3 += bf2f((unsigned short)(v0.y >> 16));
  }
  a0 += __shfl_down(a0, 32);
  a1 += __shfl_down(a1, 32);
  a2 += __shfl_down(a2, 32);
  a3 += __shfl_down(a3, 32);
  if (half == 0) {
    uint2 o;
    o.x = (unsigned)f2bf(a0) | ((unsigned)f2bf(a1) << 16);
    o.y = (unsigned)f2bf(a2) | ((unsigned)f2bf(a3) << 16);
    *reinterpret_cast<uint2*>(aggb + (size_t)node * 128 + cg) = o;
  }
}

// lineout = hidden @ line_w^T + line_b
__global__ __launch_bounds__(256) void lineout_k(
    const float* __restrict__ hidden, const float* __restrict__ W,
    const float* __restrict__ b, float* __restrict__ out) {
  __shared__ float Ws[16 * 128];
  for (int i = threadIdx.x; i < 2048; i += 256) Ws[i] = W[i];
  __syncthreads();
  int r = threadIdx.x >> 4, c = threadIdx.x & 15;
  int n = blockIdx.x * 16 + r;
  if (n >= N_NODES) return;
  const float* h = hidden + (size_t)n * 128;
  const float* w = Ws + c * 128;
  float acc = 0.f;
#pragma unroll 8
  for (int k = 0; k < 128; k++) acc += h[k] * w[k];
  out[(size_t)n * 16 + c] = acc + b[c];
}

// gate[n] = hidden[n] . gate_w + gate_b
__global__ __launch_bounds__(256) void gate_k(
    const float* __restrict__ hidden, const float* __restrict__ gw,
    const float* __restrict__ gb, float* __restrict__ gate) {
  int wid = (blockIdx.x * 256 + threadIdx.x) >> 6;
  int lane = threadIdx.x & 63;
  if (wid >= N_NODES) return;
  const float* h = hidden + (size_t)wid * 128;
  float s = h[lane] * gw[lane] + h[64 + lane] * gw[64 + lane];
#pragma unroll
  for (int off = 32; off; off >>= 1) s += __shfl_down(s, off);
  if (lane == 0) gate[wid] = s + gb[0];
}

// gs[g] = lower_bound(batch, g)
__global__ void graph_start_k(const int* __restrict__ batch, int* __restrict__ gs) {
  int g = threadIdx.x;
  if (g > 512) return;
  if (g == 512) {
    gs[512] = N_NODES;
    return;
  }
  int lo = 0, hi = N_NODES;
  while (lo < hi) {
    int mid = (lo + hi) >> 1;
    if (batch[mid] < g) lo = mid + 1;
    else hi = mid;
  }
  gs[g] = lo;
}

// ---------------------------------------------------------------------------
// Per-graph attention pool (batch sorted, no atomics)
// ---------------------------------------------------------------------------
__global__ __launch_bounds__(256) void pool_fused_k(
    const float* __restrict__ hidden, const float* __restrict__ gate,
    const int* __restrict__ gs, float* __restrict__ ex,
    float* __restrict__ pooled) {
  const int g = blockIdx.x;
  const int beg = gs[g], end = gs[g + 1];
  const int tid = threadIdx.x, lane = tid & 63, wv = tid >> 6;
  __shared__ float red[4];
  __shared__ float sval;
  __shared__ float colbuf[256];

  if (end <= beg) {
    if (tid < 128) pooled[(size_t)g * 128 + tid] = 0.f;
    return;
  }
  float m = -3.4e38f;
  for (int n = beg + tid; n < end; n += 256) m = fmaxf(m, gate[n]);
#pragma unroll
  for (int off = 32; off; off >>= 1) m = fmaxf(m, __shfl_down(m, off));
  if (lane == 0) red[wv] = m;
  __syncthreads();
  if (tid == 0) sval = fmaxf(fmaxf(red[0], red[1]), fmaxf(red[2], red[3]));
  __syncthreads();
  const float mx = sval;
  float s = 0.f;
  for (int n = beg + tid; n < end; n += 256) {
    float e = __expf(gate[n] - mx);
    ex[n] = e;
    s += e;
  }
#pragma unroll
  for (int off = 32; off; off >>= 1) s += __shfl_down(s, off);
  if (lane == 0) red[wv] = s;
  __syncthreads();
  if (tid == 0) sval = red[0] + red[1] + red[2] + red[3];
  __syncthreads();
  const float denom = sval;
  const int col = tid & 127, half = tid >> 7;
  float acc = 0.f;
  for (int n = beg + half; n < end; n += 2)
    acc += ex[n] * hidden[(size_t)n * 128 + col];
  colbuf[tid] = acc;
  __syncthreads();
  if (tid < 128)
    pooled[(size_t)g * 128 + tid] = (colbuf[tid] + colbuf[tid + 128]) / denom;
}

__global__ void mlp1_k(const float* __restrict__ pooled, const float* __restrict__ w,
                       const float* __restrict__ b, float* __restrict__ h1) {
  int g = blockIdx.x, j = threadIdx.x;
  const float* p = pooled + (size_t)g * 128;
  const float* wr = w + (size_t)j * 128;
  float acc = 0.f;
#pragma unroll 8
  for (int k = 0; k < 128; k++) acc += p[k] * wr[k];
  acc += b[j];
  h1[g * 64 + j] = acc > 0.f ? acc : 0.f;
}

__global__ void mlp2_k(const float* __restrict__ h1, const float* __restrict__ w,
                       const float* __restrict__ b, float* __restrict__ h2) {
  int g = blockIdx.x, j = threadIdx.x;
  const float* p = h1 + (size_t)g * 64;
  const float* wr = w + (size_t)j * 64;
  float acc = 0.f;
#pragma unroll 8
  for (int k = 0; k < 64; k++) acc += p[k] * wr[k];
  acc += b[j];
  h2[g * 64 + j] = acc > 0.f ? acc : 0.f;
}

__global__ void outhead_k(const float* __restrict__ h2, const float* __restrict__ w,
                          const float* __restrict__ b, float* __restrict__ out) {
  int g = blockIdx.x, j = threadIdx.x;
  if (j >= 16) return;
  const float* p = h2 + (size_t)g * 64;
  const float* wr = w + (size_t)j * 64;
  float acc = 0.f;
#pragma unroll 8
  for (int k = 0; k < 64; k++) acc += p[k] * wr[k];
  out[g * 16 + j] = acc + b[j];
}

extern "C" void kernel_launch(void* const* d_in, const int* in_sizes, int n_in,
                              void* d_out, int out_size, void* d_ws, size_t ws_size,
                              hipStream_t stream) {
  const float* node_embed = (const float*)d_in[0];
  const int* eidx = (const int*)d_in[1];
  const int* batch = (const int*)d_in[2];
  const float* node_w = (const float*)d_in[3];
  const float* node_b = (const float*)d_in[4];
  const float* ggc_w = (const float*)d_in[5];
  const float* w_ih = (const float*)d_in[6];
  const float* w_hh = (const float*)d_in[7];
  const float* b_ih = (const float*)d_in[8];
  const float* b_hh = (const float*)d_in[9];
  const float* cat_w = (const float*)d_in[10];
  const float* cat_b = (const float*)d_in[11];
  const float* gate_w = (const float*)d_in[12];
  const float* gate_b = (const float*)d_in[13];
  const float* mlp_w1 = (const float*)d_in[14];
  const float* mlp_b1 = (const float*)d_in[15];
  const float* mlp_w2 = (const float*)d_in[16];
  const float* mlp_b2 = (const float*)d_in[17];
  const float* out_w = (const float*)d_in[18];
  const float* out_b = (const float*)d_in[19];
  const float* line_w = (const float*)d_in[20];
  const float* line_b = (const float*)d_in[21];

  const int* src = eidx;
  const int* dst = eidx + N_EDGES;

  // workspace ~240 MB:
  // h0b [NH] | X0 [4][NH] | X1 [4][NH] (bf16 ping-pong) | wctb|whhb|wcatb | CSR
  // overlays: WcTf fp32 (pre-loop) on X0; hidden f32 (post-chain) on X0;
  //           gate/ex/pooled/h1/h2 (post-cat) on X1; aggTmp (step 0) on X1.
  unsigned short* h0b = (unsigned short*)d_ws;
  unsigned short* X0 = h0b + (size_t)NH;            // 4NH bf16
  unsigned short* X1 = X0 + (size_t)4 * NH;         // 4NH bf16
  unsigned short* wctb = X1 + (size_t)4 * NH;       // 16*384*128
  unsigned short* whhb = wctb + 16 * 384 * 128;     // 4*384*128
  unsigned short* wcatb = whhb + 4 * 384 * 128;     // 128*512
  int* offsets = (int*)(wcatb + 128 * 512);         // [N+1]
  int* cursor = offsets + N_NODES + 1;              // [N]
  int* srcs_sorted = cursor + N_NODES;              // [E]
  int* bsum = srcs_sorted + N_EDGES;                // [512]
  int* gs = bsum + 512;                             // [513]
  float* WcTf = (float*)X0;                         // fp32 staging (pre-loop)
  unsigned short* aggTmp = X1;                      // step-0 shared agg (first NH)
  float* hidden = (float*)X0;                       // post-chain overlay

  float* out_graph = (float*)d_out;
  float* out_line = (float*)d_out + 512 * 16;

  dim3 blk(256);
  const int gM128 = (N_NODES + 127) / 128;
  const int gM64 = (N_NODES + 63) / 64;
  const int gE = (N_EDGES + 255) / 256;
  const int nScanBlk = (N_NODES + 255) / 256;
  const int nRowTiles = N_NODES / 16;  // 6250, exact
  const size_t S = (size_t)384 * 128;

  // ---- CSR build ----
  hipMemsetAsync(cursor, 0, N_NODES * sizeof(int), stream);
  deg_hist_k<<<gE, blk, 0, stream>>>(dst, cursor);
  scan1_k<<<nScanBlk, blk, 0, stream>>>(cursor, offsets, bsum);
  scan2_k<<<1, 512, 0, stream>>>(bsum, nScanBlk);
  scan3_k<<<nScanBlk, blk, 0, stream>>>(offsets, bsum);
  copy_int_k<<<(N_NODES + 255) / 256, blk, 0, stream>>>(offsets, cursor, N_NODES);
  fill_k<<<gE, blk, 0, stream>>>(src, dst, cursor, srcs_sorted);
  graph_start_k<<<1, 576, 0, stream>>>(batch, gs);

  // ---- weights: WcT fold -> bf16; w_hh, cat_w -> bf16 ----
  gemm_wct_k<<<dim3(3, 2, 16), blk, 0, stream>>>(w_ih, ggc_w, WcTf);
  f2b_k<<<(16 * 384 * 128 / 4 + 255) / 256, blk, 0, stream>>>(WcTf, wctb, 16 * 384 * 128);
  f2b_k<<<(4 * 384 * 128 / 4 + 255) / 256, blk, 0, stream>>>(w_hh, whhb, 4 * 384 * 128);
  f2b_k<<<(128 * 512 / 4 + 255) / 256, blk, 0, stream>>>(cat_w, wcatb, 128 * 512);

  // ---- h0b = bf16(node_embed @ node_w^T + node_b) ----
  gemm_h0_k<<<dim3(gM128, 2), blk, 0, stream>>>(node_embed, node_w, node_b, h0b, N_NODES);

  // ---- 4 independent GGC chains, batched; gather fused (steps 1..3) ----
  const dim3 G8(1024, 4);
  // step 0: shared gather (all chains read h0b) -> aggTmp; GAGG gru
  gather5_k<<<(N_NODES * 64 + 255) / 256, blk, 0, stream>>>(h0b, offsets, srcs_sorted, aggTmp);
  gru_fused8_k<true, false><<<G8, 512, 0, stream>>>(
      aggTmp, 0, h0b, 0, h0b, offsets, srcs_sorted, wctb, 4 * S, whhb, S,
      b_ih, b_hh, X0, nRowTiles);
  // step 1: X0 -> X1 (fused gather)
  gru_fused8_k<false, false><<<G8, 512, 0, stream>>>(
      nullptr, 0, X0, NH, h0b, offsets, srcs_sorted, wctb + S, 4 * S, whhb, S,
      b_ih, b_hh, X1, nRowTiles);
  // step 2: X1 -> X0
  gru_fused8_k<false, false><<<G8, 512, 0, stream>>>(
      nullptr, 0, X1, NH, h0b, offsets, srcs_sorted, wctb + 2 * S, 4 * S, whhb, S,
      b_ih, b_hh, X0, nRowTiles);
  // step 3 (LAST): X0 -> X1 = bf16(x_new + h0)
  gru_fused8_k<false, true><<<G8, 512, 0, stream>>>(
      nullptr, 0, X0, NH, h0b, offsets, srcs_sorted, wctb + 3 * S, 4 * S, whhb, S,
      b_ih, b_hh, X1, nRowTiles);

  // ---- hidden = concat(X1) @ cat_w^T + cat_b ----
  cat_full_k<<<dim3(gM64, 4), blk, 0, stream>>>(X1, wcatb, cat_b, hidden, N_NODES);

  // ---- heads ----
  lineout_k<<<(N_NODES + 15) / 16, blk, 0, stream>>>(hidden, line_w, line_b, out_line);

  float* gate = (float*)X1;
  float* ex = (float*)X1 + N_NODES;
  float* pooled = ex + N_NODES;
  float* h1 = pooled + 512 * 128;
  float* h2 = h1 + 512 * 64;

  gate_k<<<(N_NODES * 64 + 255) / 256, blk, 0, stream>>>(hidden, gate_w, gate_b, gate);
  pool_fused_k<<<512, blk, 0, stream>>>(hidden, gate, gs, ex, pooled);
  mlp1_k<<<512, 64, 0, stream>>>(pooled, mlp_w1, mlp_b1, h1);
  mlp2_k<<<512, 64, 0, stream>>>(h1, mlp_w2, mlp_b2, h2);
  outhead_k<<<512, 64, 0, stream>>>(h2, out_w, out_b, out_graph);
}

// Round 13
// 2309.524 us; speedup vs baseline: 1.7121x; 1.7121x over previous
//
#include <hip/hip_runtime.h>

#define N_NODES 100000
#define N_EDGES 1600000
#define HD 128
#define NH (N_NODES * HD)

typedef __attribute__((ext_vector_type(8))) short bf16x8;
typedef __attribute__((ext_vector_type(4))) float f32x4;

__device__ inline unsigned short f2bf(float f) {
  unsigned u = __float_as_uint(f);
  unsigned r = (u + 0x7FFFu + ((u >> 16) & 1u)) >> 16;
  return (unsigned short)r;
}
__device__ inline float bf2f(unsigned short b) {
  return __uint_as_float(((unsigned)b) << 16);
}
__device__ inline float sigm_f(float x) {
  return __builtin_amdgcn_rcpf(1.f + __expf(-x));
}
__device__ inline float tanh_f(float x) {
  return 1.f - 2.f * __builtin_amdgcn_rcpf(__expf(2.f * x) + 1.f);
}

// ---------------------------------------------------------------------------
// h0 GEMM: h0b = bf16(node_embed @ node_w^T + node_b)
// ---------------------------------------------------------------------------
__global__ __launch_bounds__(256) void gemm_h0_k(
    const float* __restrict__ A, const float* __restrict__ B,
    const float* __restrict__ bias, unsigned short* __restrict__ Cb, int M) {
  __shared__ float As[16][132];
  __shared__ float Bs[16][68];
  const int tid = threadIdx.x;
  const int row0 = blockIdx.x * 128;
  const int col0 = blockIdx.y * 64;
  const int tx = tid & 15, ty = tid >> 4;

  float acc[8][4];
#pragma unroll
  for (int i = 0; i < 8; i++)
#pragma unroll
    for (int j = 0; j < 4; j++) acc[i][j] = 0.f;

  const int lr = tid >> 2;
  const int kg = (tid & 3) * 4;

  for (int k0 = 0; k0 < 128; k0 += 16) {
#pragma unroll
    for (int h = 0; h < 2; ++h) {
      int r = lr + h * 64;
      float4 v = make_float4(0.f, 0.f, 0.f, 0.f);
      if (row0 + r < M)
        v = *reinterpret_cast<const float4*>(A + (size_t)(row0 + r) * 128 + k0 + kg);
      As[kg + 0][r] = v.x;
      As[kg + 1][r] = v.y;
      As[kg + 2][r] = v.z;
      As[kg + 3][r] = v.w;
    }
    {
      int c = lr;
      float4 v = *reinterpret_cast<const float4*>(B + (size_t)(col0 + c) * 128 + k0 + kg);
      Bs[kg + 0][c] = v.x;
      Bs[kg + 1][c] = v.y;
      Bs[kg + 2][c] = v.z;
      Bs[kg + 3][c] = v.w;
    }
    __syncthreads();
#pragma unroll
    for (int kk = 0; kk < 16; ++kk) {
      float a[8], b[4];
#pragma unroll
      for (int i = 0; i < 8; i++) a[i] = As[kk][ty * 8 + i];
#pragma unroll
      for (int j = 0; j < 4; j++) b[j] = Bs[kk][tx * 4 + j];
#pragma unroll
      for (int i = 0; i < 8; i++)
#pragma unroll
        for (int j = 0; j < 4; j++) acc[i][j] += a[i] * b[j];
    }
    __syncthreads();
  }

#pragma unroll
  for (int i = 0; i < 8; i++) {
    int r = row0 + ty * 8 + i;
    if (r < M) {
#pragma unroll
      for (int j = 0; j < 4; j++) {
        int c = col0 + tx * 4 + j;
        Cb[(size_t)r * 128 + c] = f2bf(acc[i][j] + bias[c]);
      }
    }
  }
}

// ---------------------------------------------------------------------------
// Batched WcT fold: C[z] = w_ih[z>>2] @ ggc_w[z]^T   ([384,128] each, z=0..15)
// ---------------------------------------------------------------------------
__global__ __launch_bounds__(256) void gemm_wct_k(
    const float* __restrict__ w_ih, const float* __restrict__ ggc_w,
    float* __restrict__ Cout) {
  const int z = blockIdx.z;
  const float* A = w_ih + (size_t)(z >> 2) * 384 * 128;
  const float* B = ggc_w + (size_t)z * 128 * 128;
  float* C = Cout + (size_t)z * 384 * 128;
  __shared__ float As[16][132];
  __shared__ float Bs[16][68];
  const int tid = threadIdx.x;
  const int row0 = blockIdx.x * 128;
  const int col0 = blockIdx.y * 64;
  const int tx = tid & 15, ty = tid >> 4;

  float acc[8][4];
#pragma unroll
  for (int i = 0; i < 8; i++)
#pragma unroll
    for (int j = 0; j < 4; j++) acc[i][j] = 0.f;

  const int lr = tid >> 2;
  const int kg = (tid & 3) * 4;

  for (int k0 = 0; k0 < 128; k0 += 16) {
#pragma unroll
    for (int h = 0; h < 2; ++h) {
      int r = lr + h * 64;
      float4 v = *reinterpret_cast<const float4*>(A + (size_t)(row0 + r) * 128 + k0 + kg);
      As[kg + 0][r] = v.x;
      As[kg + 1][r] = v.y;
      As[kg + 2][r] = v.z;
      As[kg + 3][r] = v.w;
    }
    {
      int c = lr;
      float4 v = *reinterpret_cast<const float4*>(B + (size_t)(col0 + c) * 128 + k0 + kg);
      Bs[kg + 0][c] = v.x;
      Bs[kg + 1][c] = v.y;
      Bs[kg + 2][c] = v.z;
      Bs[kg + 3][c] = v.w;
    }
    __syncthreads();
#pragma unroll
    for (int kk = 0; kk < 16; ++kk) {
      float a[8], b[4];
#pragma unroll
      for (int i = 0; i < 8; i++) a[i] = As[kk][ty * 8 + i];
#pragma unroll
      for (int j = 0; j < 4; j++) b[j] = Bs[kk][tx * 4 + j];
#pragma unroll
      for (int i = 0; i < 8; i++)
#pragma unroll
        for (int j = 0; j < 4; j++) acc[i][j] += a[i] * b[j];
    }
    __syncthreads();
  }

#pragma unroll
  for (int i = 0; i < 8; i++) {
    int r = row0 + ty * 8 + i;
#pragma unroll
    for (int j = 0; j < 4; j++) {
      int c = col0 + tx * 4 + j;
      C[(size_t)r * 128 + c] = acc[i][j];
    }
  }
}

// ---------------------------------------------------------------------------
// float -> bf16, 4 elems/thread
// ---------------------------------------------------------------------------
__global__ __launch_bounds__(256) void f2b_k(const float* __restrict__ a,
                                             unsigned short* __restrict__ b, int n) {
  int i = blockIdx.x * 256 + threadIdx.x;
  if (i * 4 >= n) return;
  float4 v = reinterpret_cast<const float4*>(a)[i];
  ushort4 o;
  o.x = f2bf(v.x);
  o.y = f2bf(v.y);
  o.z = f2bf(v.z);
  o.w = f2bf(v.w);
  reinterpret_cast<ushort4*>(b)[i] = o;
}

// ---------------------------------------------------------------------------
// GRU v7b: round-11 structure, but __launch_bounds__(512, 2) so the 24
// weight fragments (96 VGPR) stay RESIDENT across the row-tile loop
// (round-11's VGPR_Count=84 proved the compiler was re-loading them).
// 4-way chain-batched (blockIdx.y = chain), IN-PLACE state update; one
// __syncthreads() between cross-col fragment reads and per-col stores.
// ---------------------------------------------------------------------------
template <bool LAST>
__global__ __launch_bounds__(512, 2) void gru_mfma7_k(
    const unsigned short* __restrict__ agg_base, size_t agg_zs,
    const unsigned short* __restrict__ xb_base, size_t xb_zs,
    const unsigned short* __restrict__ h0b,
    const unsigned short* __restrict__ wct_base, size_t wct_zs,
    const unsigned short* __restrict__ whh_base, size_t whh_zs,
    const float* __restrict__ bih_base, const float* __restrict__ bhh_base,
    unsigned short* __restrict__ Xout, int nRowTiles) {
  const int z = blockIdx.y;
  const unsigned short* agg = agg_base + (size_t)z * agg_zs;
  const unsigned short* xb = xb_base + (size_t)z * xb_zs;
  unsigned short* out = Xout + (size_t)z * NH;
  const unsigned short* wctb = wct_base + (size_t)z * wct_zs;
  const unsigned short* whhb = whh_base + (size_t)z * whh_zs;
  const float* b_ih = bih_base + z * 384;
  const float* b_hh = bhh_base + z * 384;

  const int lane = threadIdx.x & 63;
  const int wave = threadIdx.x >> 6;  // 0..7 -> col tile
  const int lrow = lane & 15;
  const int kblk = lane >> 4;  // 0..3
  const int c = wave * 16 + lrow;

  bf16x8 wf[6][4];
#pragma unroll
  for (int s = 0; s < 3; s++)
#pragma unroll
    for (int kk = 0; kk < 4; kk++) {
      size_t off = (size_t)(s * 128 + c) * 128 + kk * 32 + kblk * 8;
      wf[s][kk] = *reinterpret_cast<const bf16x8*>(wctb + off);
      wf[s + 3][kk] = *reinterpret_cast<const bf16x8*>(whhb + off);
    }
  const float bi0 = b_ih[c], bi1 = b_ih[128 + c], bi2 = b_ih[256 + c];
  const float bh0 = b_hh[c], bh1 = b_hh[128 + c], bh2 = b_hh[256 + c];

  for (int rt = blockIdx.x; rt < nRowTiles; rt += gridDim.x) {
    const int row0 = rt * 16;  // N_NODES % 16 == 0 -> rows in-bounds
    const size_t abase = (size_t)(row0 + lrow) * 128 + kblk * 8;

    f32x4 acc[6];
#pragma unroll
    for (int s = 0; s < 6; s++) acc[s] = (f32x4)(0.f);
#pragma unroll
    for (int kk = 0; kk < 4; kk++) {
      bf16x8 a_ag = *reinterpret_cast<const bf16x8*>(agg + abase + kk * 32);
      bf16x8 a_x = *reinterpret_cast<const bf16x8*>(xb + abase + kk * 32);
      acc[0] = __builtin_amdgcn_mfma_f32_16x16x32_bf16(a_ag, wf[0][kk], acc[0], 0, 0, 0);
      acc[1] = __builtin_amdgcn_mfma_f32_16x16x32_bf16(a_ag, wf[1][kk], acc[1], 0, 0, 0);
      acc[2] = __builtin_amdgcn_mfma_f32_16x16x32_bf16(a_ag, wf[2][kk], acc[2], 0, 0, 0);
      acc[3] = __builtin_amdgcn_mfma_f32_16x16x32_bf16(a_x, wf[3][kk], acc[3], 0, 0, 0);
      acc[4] = __builtin_amdgcn_mfma_f32_16x16x32_bf16(a_x, wf[4][kk], acc[4], 0, 0, 0);
      acc[5] = __builtin_amdgcn_mfma_f32_16x16x32_bf16(a_x, wf[5][kk], acc[5], 0, 0, 0);
    }
    // all cross-col reads of this tile are consumed; make stores safe
    __syncthreads();
    // C/D: col = lane&15 (= lrow -> c), row = kblk*4 + r
#pragma unroll
    for (int r = 0; r < 4; r++) {
      int orow = row0 + kblk * 4 + r;
      size_t idx = (size_t)orow * 128 + c;
      float ir = acc[0][r] + bi0;
      float iz = acc[1][r] + bi1;
      float in_ = acc[2][r] + bi2;
      float hr = acc[3][r] + bh0;
      float hz = acc[4][r] + bh1;
      float hn = acc[5][r] + bh2;
      float rg = sigm_f(ir + hr);
      float zg = sigm_f(iz + hz);
      float ng = tanh_f(in_ + rg * hn);
      float h = bf2f(xb[idx]);  // own column: written only by this lane, below
      float nv = (1.f - zg) * ng + zg * h;
      if (LAST) nv += bf2f(h0b[idx]);
      out[idx] = f2bf(nv);
    }
  }
}

// ---------------------------------------------------------------------------
// cat full: hidden = concat(X[0..3]) @ cat_w^T + cat_b  (K=512, one pass)
// ---------------------------------------------------------------------------
__global__ __launch_bounds__(256) void cat_full_k(
    const unsigned short* __restrict__ X,      // [4][NH] (outs, residual fused)
    const unsigned short* __restrict__ wcatb,  // [128][512]
    const float* __restrict__ cat_b, float* __restrict__ hidden, int M) {
  const int lane = threadIdx.x & 63;
  const int wave = threadIdx.x >> 6;
  const int row0 = blockIdx.x * 64 + wave * 16;
  const int c0 = blockIdx.y * 32;
  const int lrow = lane & 15;
  const int kb = lane >> 4;
  int arow = row0 + lrow;
  if (arow >= M) arow = M - 1;

  f32x4 acc[2];
  acc[0] = (f32x4)(0.f);
  acc[1] = (f32x4)(0.f);
#pragma unroll
  for (int kk = 0; kk < 16; kk++) {
    const unsigned short* ob = X + (size_t)(kk >> 2) * NH;
    bf16x8 a = *reinterpret_cast<const bf16x8*>(
        ob + (size_t)arow * 128 + (kk & 3) * 32 + kb * 8);
#pragma unroll
    for (int t = 0; t < 2; t++) {
      bf16x8 b = *reinterpret_cast<const bf16x8*>(
          wcatb + (size_t)(c0 + t * 16 + lrow) * 512 + (kk >> 2) * 128 +
          (kk & 3) * 32 + kb * 8);
      acc[t] = __builtin_amdgcn_mfma_f32_16x16x32_bf16(a, b, acc[t], 0, 0, 0);
    }
  }
#pragma unroll
  for (int r = 0; r < 4; r++) {
    int orow = row0 + kb * 4 + r;
    if (orow >= M) continue;
#pragma unroll
    for (int t = 0; t < 2; t++) {
      int c = c0 + t * 16 + lrow;
      hidden[(size_t)orow * 128 + c] = acc[t][r] + cat_b[c];
    }
  }
}

// ---------------------------------------------------------------------------
// CSR build
// ---------------------------------------------------------------------------
__global__ __launch_bounds__(256) void deg_hist_k(const int* __restrict__ dst,
                                                  int* __restrict__ deg) {
  int e = blockIdx.x * 256 + threadIdx.x;
  if (e >= N_EDGES) return;
  atomicAdd(&deg[dst[e]], 1);
}

__global__ __launch_bounds__(256) void scan1_k(const int* __restrict__ deg,
                                               int* __restrict__ offsets,
                                               int* __restrict__ bsum) {
  __shared__ int buf[256];
  int tid = threadIdx.x;
  int idx = blockIdx.x * 256 + tid;
  int v = (idx < N_NODES) ? deg[idx] : 0;
  buf[tid] = v;
  __syncthreads();
  for (int off = 1; off < 256; off <<= 1) {
    int t = (tid >= off) ? buf[tid - off] : 0;
    __syncthreads();
    buf[tid] += t;
    __syncthreads();
  }
  if (idx < N_NODES) offsets[idx] = buf[tid] - v;
  if (tid == 255) bsum[blockIdx.x] = buf[255];
}

__global__ __launch_bounds__(512) void scan2_k(int* __restrict__ bsum, int nb) {
  __shared__ int buf[512];
  int tid = threadIdx.x;
  int v = (tid < nb) ? bsum[tid] : 0;
  buf[tid] = v;
  __syncthreads();
  for (int off = 1; off < 512; off <<= 1) {
    int t = (tid >= off) ? buf[tid - off] : 0;
    __syncthreads();
    buf[tid] += t;
    __syncthreads();
  }
  if (tid < nb) bsum[tid] = buf[tid] - v;
}

__global__ __launch_bounds__(256) void scan3_k(int* __restrict__ offsets,
                                               const int* __restrict__ bsum) {
  int idx = blockIdx.x * 256 + threadIdx.x;
  if (idx < N_NODES) offsets[idx] += bsum[idx >> 8];
  if (idx == 0) offsets[N_NODES] = N_EDGES;
}

__global__ __launch_bounds__(256) void copy_int_k(const int* __restrict__ a,
                                                  int* __restrict__ b, int n) {
  int i = blockIdx.x * 256 + threadIdx.x;
  if (i < n) b[i] = a[i];
}

__global__ __launch_bounds__(256) void fill_k(const int* __restrict__ src,
                                              const int* __restrict__ dst,
                                              int* __restrict__ cursor,
                                              int* __restrict__ srcs_sorted) {
  int e = blockIdx.x * 256 + threadIdx.x;
  if (e >= N_EDGES) return;
  int pos = atomicAdd(&cursor[dst[e]], 1);
  srcs_sorted[pos] = src[e];
}

// ---------------------------------------------------------------------------
// gather: nz chains (1 or 4), wave per (z,node); lanes split 32/32 over
// even/odd edges; 4 row loads in flight per half-wave.
// ---------------------------------------------------------------------------
__global__ __launch_bounds__(256) void gather5_k(
    const unsigned short* __restrict__ xb_base, size_t xstride,
    const int* __restrict__ offsets, const int* __restrict__ srcs,
    unsigned short* __restrict__ aggb, int nz) {
  int wid = (blockIdx.x * 256 + threadIdx.x) >> 6;
  int lane = threadIdx.x & 63;
  if (wid >= nz * N_NODES) return;
  int z = 0, node = wid;
  if (node >= 2 * N_NODES) { z = 2; node -= 2 * N_NODES; }
  if (node >= N_NODES) { z += 1; node -= N_NODES; }
  const unsigned short* xb = xb_base + (size_t)z * xstride;
  int beg = offsets[node], end = offsets[node + 1];
  int half = lane >> 5;
  int cg = (lane & 31) * 4;
  float a0 = 0.f, a1 = 0.f, a2 = 0.f, a3 = 0.f;
  int e = beg + half;
  for (; e + 6 < end; e += 8) {
    int s0 = srcs[e], s1 = srcs[e + 2], s2 = srcs[e + 4], s3 = srcs[e + 6];
    uint2 v0 = *reinterpret_cast<const uint2*>(xb + (size_t)s0 * 128 + cg);
    uint2 v1 = *reinterpret_cast<const uint2*>(xb + (size_t)s1 * 128 + cg);
    uint2 v2 = *reinterpret_cast<const uint2*>(xb + (size_t)s2 * 128 + cg);
    uint2 v3 = *reinterpret_cast<const uint2*>(xb + (size_t)s3 * 128 + cg);
    a0 += bf2f((unsigned short)(v0.x & 0xFFFFu)) + bf2f((unsigned short)(v1.x & 0xFFFFu)) +
          bf2f((unsigned short)(v2.x & 0xFFFFu)) + bf2f((unsigned short)(v3.x & 0xFFFFu));
    a1 += bf2f((unsigned short)(v0.x >> 16)) + bf2f((unsigned short)(v1.x >> 16)) +
          bf2f((unsigned short)(v2.x >> 16)) + bf2f((unsigned short)(v3.x >> 16));
    a2 += bf2f((unsigned short)(v0.y & 0xFFFFu)) + bf2f((unsigned short)(v1.y & 0xFFFFu)) +
          bf2f((unsigned short)(v2.y & 0xFFFFu)) + bf2f((unsigned short)(v3.y & 0xFFFFu));
    a3 += bf2f((unsigned short)(v0.y >> 16)) + bf2f((unsigned short)(v1.y >> 16)) +
          bf2f((unsigned short)(v2.y >> 16)) + bf2f((unsigned short)(v3.y >> 16));
  }
  for (; e < end; e += 2) {
    int s0 = srcs[e];
    uint2 v0 = *reinterpret_cast<const uint2*>(xb + (size_t)s0 * 128 + cg);
    a0 += bf2f((unsigned short)(v0.x & 0xFFFFu));
    a1 += bf2f((unsigned short)(v0.x >> 16));
    a2 += bf2f((unsigned short)(v0.y & 0xFFFFu));
    a3 += bf2f((unsigned short)(v0.y >> 16));
  }
  a0 += __shfl_down(a0, 32);
  a1 += __shfl_down(a1, 32);
  a2 += __shfl_down(a2, 32);
  a3 += __shfl_down(a3, 32);
  if (half == 0) {
    uint2 o;
    o.x = (unsigned)f2bf(a0) | ((unsigned)f2bf(a1) << 16);
    o.y = (unsigned)f2bf(a2) | ((unsigned)f2bf(a3) << 16);
    *reinterpret_cast<uint2*>(aggb + (size_t)z * NH + (size_t)node * 128 + cg) = o;
  }
}

// lineout = hidden @ line_w^T + line_b
__global__ __launch_bounds__(256) void lineout_k(
    const float* __restrict__ hidden, const float* __restrict__ W,
    const float* __restrict__ b, float* __restrict__ out) {
  __shared__ float Ws[16 * 128];
  for (int i = threadIdx.x; i < 2048; i += 256) Ws[i] = W[i];
  __syncthreads();
  int r = threadIdx.x >> 4, c = threadIdx.x & 15;
  int n = blockIdx.x * 16 + r;
  if (n >= N_NODES) return;
  const float* h = hidden + (size_t)n * 128;
  const float* w = Ws + c * 128;
  float acc = 0.f;
#pragma unroll 8
  for (int k = 0; k < 128; k++) acc += h[k] * w[k];
  out[(size_t)n * 16 + c] = acc + b[c];
}

// gate[n] = hidden[n] . gate_w + gate_b
__global__ __launch_bounds__(256) void gate_k(
    const float* __restrict__ hidden, const float* __restrict__ gw,
    const float* __restrict__ gb, float* __restrict__ gate) {
  int wid = (blockIdx.x * 256 + threadIdx.x) >> 6;
  int lane = threadIdx.x & 63;
  if (wid >= N_NODES) return;
  const float* h = hidden + (size_t)wid * 128;
  float s = h[lane] * gw[lane] + h[64 + lane] * gw[64 + lane];
#pragma unroll
  for (int off = 32; off; off >>= 1) s += __shfl_down(s, off);
  if (lane == 0) gate[wid] = s + gb[0];
}

// gs[g] = lower_bound(batch, g)
__global__ void graph_start_k(const int* __restrict__ batch, int* __restrict__ gs) {
  int g = threadIdx.x;
  if (g > 512) return;
  if (g == 512) {
    gs[512] = N_NODES;
    return;
  }
  int lo = 0, hi = N_NODES;
  while (lo < hi) {
    int mid = (lo + hi) >> 1;
    if (batch[mid] < g) lo = mid + 1;
    else hi = mid;
  }
  gs[g] = lo;
}

// ---------------------------------------------------------------------------
// Per-graph attention pool (batch sorted, no atomics)
// ---------------------------------------------------------------------------
__global__ __launch_bounds__(256) void pool_fused_k(
    const float* __restrict__ hidden, const float* __restrict__ gate,
    const int* __restrict__ gs, float* __restrict__ ex,
    float* __restrict__ pooled) {
  const int g = blockIdx.x;
  const int beg = gs[g], end = gs[g + 1];
  const int tid = threadIdx.x, lane = tid & 63, wv = tid >> 6;
  __shared__ float red[4];
  __shared__ float sval;
  __shared__ float colbuf[256];

  if (end <= beg) {
    if (tid < 128) pooled[(size_t)g * 128 + tid] = 0.f;
    return;
  }
  float m = -3.4e38f;
  for (int n = beg + tid; n < end; n += 256) m = fmaxf(m, gate[n]);
#pragma unroll
  for (int off = 32; off; off >>= 1) m = fmaxf(m, __shfl_down(m, off));
  if (lane == 0) red[wv] = m;
  __syncthreads();
  if (tid == 0) sval = fmaxf(fmaxf(red[0], red[1]), fmaxf(red[2], red[3]));
  __syncthreads();
  const float mx = sval;
  float s = 0.f;
  for (int n = beg + tid; n < end; n += 256) {
    float e = __expf(gate[n] - mx);
    ex[n] = e;
    s += e;
  }
#pragma unroll
  for (int off = 32; off; off >>= 1) s += __shfl_down(s, off);
  if (lane == 0) red[wv] = s;
  __syncthreads();
  if (tid == 0) sval = red[0] + red[1] + red[2] + red[3];
  __syncthreads();
  const float denom = sval;
  const int col = tid & 127, half = tid >> 7;
  float acc = 0.f;
  for (int n = beg + half; n < end; n += 2)
    acc += ex[n] * hidden[(size_t)n * 128 + col];
  colbuf[tid] = acc;
  __syncthreads();
  if (tid < 128)
    pooled[(size_t)g * 128 + tid] = (colbuf[tid] + colbuf[tid + 128]) / denom;
}

__global__ void mlp1_k(const float* __restrict__ pooled, const float* __restrict__ w,
                       const float* __restrict__ b, float* __restrict__ h1) {
  int g = blockIdx.x, j = threadIdx.x;
  const float* p = pooled + (size_t)g * 128;
  const float* wr = w + (size_t)j * 128;
  float acc = 0.f;
#pragma unroll 8
  for (int k = 0; k < 128; k++) acc += p[k] * wr[k];
  acc += b[j];
  h1[g * 64 + j] = acc > 0.f ? acc : 0.f;
}

__global__ void mlp2_k(const float* __restrict__ h1, const float* __restrict__ w,
                       const float* __restrict__ b, float* __restrict__ h2) {
  int g = blockIdx.x, j = threadIdx.x;
  const float* p = h1 + (size_t)g * 64;
  const float* wr = w + (size_t)j * 64;
  float acc = 0.f;
#pragma unroll 8
  for (int k = 0; k < 64; k++) acc += p[k] * wr[k];
  acc += b[j];
  h2[g * 64 + j] = acc > 0.f ? acc : 0.f;
}

__global__ void outhead_k(const float* __restrict__ h2, const float* __restrict__ w,
                          const float* __restrict__ b, float* __restrict__ out) {
  int g = blockIdx.x, j = threadIdx.x;
  if (j >= 16) return;
  const float* p = h2 + (size_t)g * 64;
  const float* wr = w + (size_t)j * 64;
  float acc = 0.f;
#pragma unroll 8
  for (int k = 0; k < 64; k++) acc += p[k] * wr[k];
  out[g * 16 + j] = acc + b[j];
}

extern "C" void kernel_launch(void* const* d_in, const int* in_sizes, int n_in,
                              void* d_out, int out_size, void* d_ws, size_t ws_size,
                              hipStream_t stream) {
  const float* node_embed = (const float*)d_in[0];
  const int* eidx = (const int*)d_in[1];
  const int* batch = (const int*)d_in[2];
  const float* node_w = (const float*)d_in[3];
  const float* node_b = (const float*)d_in[4];
  const float* ggc_w = (const float*)d_in[5];
  const float* w_ih = (const float*)d_in[6];
  const float* w_hh = (const float*)d_in[7];
  const float* b_ih = (const float*)d_in[8];
  const float* b_hh = (const float*)d_in[9];
  const float* cat_w = (const float*)d_in[10];
  const float* cat_b = (const float*)d_in[11];
  const float* gate_w = (const float*)d_in[12];
  const float* gate_b = (const float*)d_in[13];
  const float* mlp_w1 = (const float*)d_in[14];
  const float* mlp_b1 = (const float*)d_in[15];
  const float* mlp_w2 = (const float*)d_in[16];
  const float* mlp_b2 = (const float*)d_in[17];
  const float* out_w = (const float*)d_in[18];
  const float* out_b = (const float*)d_in[19];
  const float* line_w = (const float*)d_in[20];
  const float* line_b = (const float*)d_in[21];

  const int* src = eidx;
  const int* dst = eidx + N_EDGES;

  // workspace ~240 MB (round-11 proven layout):
  // h0b [NH] | X [4][NH] (in-place states, then outs) | agg [4][NH]
  // | wctb | whhb | wcatb | CSR ints
  unsigned short* h0b = (unsigned short*)d_ws;
  unsigned short* X = h0b + (size_t)NH;             // 4NH bf16
  unsigned short* aggb = X + (size_t)4 * NH;        // 4NH bf16
  unsigned short* wctb = aggb + (size_t)4 * NH;     // 16*384*128
  unsigned short* whhb = wctb + 16 * 384 * 128;     // 4*384*128
  unsigned short* wcatb = whhb + 4 * 384 * 128;     // 128*512
  int* offsets = (int*)(wcatb + 128 * 512);         // [N+1]
  int* cursor = offsets + N_NODES + 1;              // [N]
  int* srcs_sorted = cursor + N_NODES;              // [E]
  int* bsum = srcs_sorted + N_EDGES;                // [512]
  int* gs = bsum + 512;                             // [513]
  float* WcTf = (float*)aggb;                       // fp32 staging (pre-loop)
  float* hidden = (float*)aggb;                     // post-loop overlay

  float* out_graph = (float*)d_out;
  float* out_line = (float*)d_out + 512 * 16;

  dim3 blk(256);
  const int gM128 = (N_NODES + 127) / 128;
  const int gM64 = (N_NODES + 63) / 64;
  const int gE = (N_EDGES + 255) / 256;
  const int nScanBlk = (N_NODES + 255) / 256;
  const int nRowTiles = N_NODES / 16;  // 6250, exact
  const size_t S = (size_t)384 * 128;

  // ---- CSR build ----
  hipMemsetAsync(cursor, 0, N_NODES * sizeof(int), stream);
  deg_hist_k<<<gE, blk, 0, stream>>>(dst, cursor);
  scan1_k<<<nScanBlk, blk, 0, stream>>>(cursor, offsets, bsum);
  scan2_k<<<1, 512, 0, stream>>>(bsum, nScanBlk);
  scan3_k<<<nScanBlk, blk, 0, stream>>>(offsets, bsum);
  copy_int_k<<<(N_NODES + 255) / 256, blk, 0, stream>>>(offsets, cursor, N_NODES);
  fill_k<<<gE, blk, 0, stream>>>(src, dst, cursor, srcs_sorted);
  graph_start_k<<<1, 576, 0, stream>>>(batch, gs);

  // ---- weights: WcT fold -> bf16; w_hh, cat_w -> bf16 ----
  gemm_wct_k<<<dim3(3, 2, 16), blk, 0, stream>>>(w_ih, ggc_w, WcTf);
  f2b_k<<<(16 * 384 * 128 / 4 + 255) / 256, blk, 0, stream>>>(WcTf, wctb, 16 * 384 * 128);
  f2b_k<<<(4 * 384 * 128 / 4 + 255) / 256, blk, 0, stream>>>(w_hh, whhb, 4 * 384 * 128);
  f2b_k<<<(128 * 512 / 4 + 255) / 256, blk, 0, stream>>>(cat_w, wcatb, 128 * 512);

  // ---- h0b = bf16(node_embed @ node_w^T + node_b) ----
  gemm_h0_k<<<dim3(gM128, 2), blk, 0, stream>>>(node_embed, node_w, node_b, h0b, N_NODES);

  // ---- 4 independent GGC chains, all batched; in-place state in X ----
  const dim3 gruGrid(128, 4);
  for (int i = 0; i < 4; i++) {
    const unsigned short* xin = (i == 0) ? h0b : X;
    const size_t xzs = (i == 0) ? 0 : (size_t)NH;
    const int nz = (i == 0) ? 1 : 4;
    const size_t agg_zs = (i == 0) ? 0 : (size_t)NH;
    gather5_k<<<(nz * N_NODES * 64 + 255) / 256, blk, 0, stream>>>(
        xin, xzs, offsets, srcs_sorted, aggb, nz);
    const unsigned short* wct_i = wctb + (size_t)i * S;  // chain z adds z*4S
    if (i < 3)
      gru_mfma7_k<false><<<gruGrid, 512, 0, stream>>>(
          aggb, agg_zs, xin, xzs, h0b, wct_i, 4 * S, whhb, S, b_ih, b_hh, X,
          nRowTiles);
    else
      gru_mfma7_k<true><<<gruGrid, 512, 0, stream>>>(
          aggb, agg_zs, xin, xzs, h0b, wct_i, 4 * S, whhb, S, b_ih, b_hh, X,
          nRowTiles);
  }

  // ---- hidden = concat(X) @ cat_w^T + cat_b (one K=512 GEMM) ----
  cat_full_k<<<dim3(gM64, 4), blk, 0, stream>>>(X, wcatb, cat_b, hidden, N_NODES);

  // ---- heads ----
  lineout_k<<<(N_NODES + 15) / 16, blk, 0, stream>>>(hidden, line_w, line_b, out_line);

  float* gate = (float*)X;
  float* ex = (float*)X + N_NODES;
  float* pooled = hidden + (size_t)NH;
  float* h1 = pooled + 512 * 128;
  float* h2 = h1 + 512 * 64;

  gate_k<<<(N_NODES * 64 + 255) / 256, blk, 0, stream>>>(hidden, gate_w, gate_b, gate);
  pool_fused_k<<<512, blk, 0, stream>>>(hidden, gate, gs, ex, pooled);
  mlp1_k<<<512, 64, 0, stream>>>(pooled, mlp_w1, mlp_b1, h1);
  mlp2_k<<<512, 64, 0, stream>>>(h1, mlp_w2, mlp_b2, h2);
  outhead_k<<<512, 64, 0, stream>>>(h2, out_w, out_b, out_graph);
}